// Round 6
// baseline (2642.160 us; speedup 1.0000x reference)
//
#include <hip/hip_runtime.h>
#include <hip/hip_bf16.h>
#include <cstdint>
#include <cstddef>

// Problem constants
#define H_    128
#define IN_   86
#define OUT_  66
#define T_    50
#define B_    8192
#define NPOSE 15

// Round-6 design: round-5 + barrier surgery + nt streams.
//  - Parity double-buffered h1/h2 LDS regions kill the WAR barriers:
//    A0 = [u(86)|pad(10)|h1_even(128)|h1_odd(128)]  (S0=360)
//    A1 = [h1(128)|h2_even(128)|h2_odd(128)]        (S1=392)
//    Step t (p=t&1): GEMMs read h1[p]/h2[p], pointwise writes [1-p].
//    Barriers/step: (A) post-staging, (C) post-L0-pointwise, (E) only t>=50.
//    (round-5 had 5; each was a full 16-wave drain)
//  - x loads / out stores use __builtin_nontemporal_* so the 140+132 MB
//    streams don't evict the 0.5 MB weight set from L2 (round-5 FETCH_SIZE
//    2.7 GB = weights re-fetched ~10x/step from L3).
//  - everything else identical to round 5: BR=16, grid 512 (2 blocks/CU),
//    8 waves/block, wave w owns units w*16..w*16+15 across all 4 gates,
//    weights bf16-hi only, activations hi/lo split (2 MFMAs).
#define K0T 7
#define K1T 8
#define KDT 4
#define NT0 32
#define NT1 32
#define NTD 5
#define S0  360   // 180 dwords = 4*45 (odd) -> 2-way bank aliasing (free)
#define S1  392   // 196 dwords = 4*49 (odd)
#define BR  16

// ws layout (bytes) — hi-only packed B fragments [ktile][ntile][lane][8bf16]
#define B0P_OFF 0
#define B0P_SZ  (K0T * NT0 * 1024)       // 229376
#define B1P_OFF (B0P_OFF + B0P_SZ)
#define B1P_SZ  (K1T * NT1 * 1024)       // 262144
#define BDP_OFF (B1P_OFF + B1P_SZ)       // 491520
#define BDP_SZ  (KDT * NTD * 1024)       // 20480
#define B0P_N (B0P_SZ / 2)
#define B1P_N (B1P_SZ / 2)
#define TOT_N ((B0P_SZ + B1P_SZ + BDP_SZ) / 2)

typedef __attribute__((ext_vector_type(8))) short bfrag;
typedef __attribute__((ext_vector_type(4))) float ffrag;

#define MFMA(AC, AA, BB) \
  AC = __builtin_amdgcn_mfma_f32_16x16x32_bf16((AA), (BB), (AC), 0, 0, 0)

__device__ __forceinline__ unsigned short bf16rn(float f) {
  union { float f; unsigned int u; } cv; cv.f = f;
  unsigned int u = cv.u;
  u += 0x7FFFu + ((u >> 16) & 1u);   // round-to-nearest-even
  return (unsigned short)(u >> 16);
}
__device__ __forceinline__ float bf16tof(unsigned short h) {
  union { unsigned int u; float f; } cv; cv.u = ((unsigned int)h) << 16;
  return cv.f;
}
__device__ __forceinline__ float sigmoid_f(float v) {
  return __fdividef(1.f, 1.f + __expf(-v));
}
__device__ __forceinline__ float tanh_f(float v) {
  float av = fabsf(v);
  float e  = __expf(-2.f * av);
  float t  = __fdividef(1.f - e, 1.f + e);
  return copysignf(t, v);
}

// ---------------- prep: pack hi-only weights in MFMA fragment order ---------
__global__ void wm_prep(
    const float* __restrict__ Wih0, const float* __restrict__ Whh0,
    const float* __restrict__ Wih1, const float* __restrict__ Whh1,
    const float* __restrict__ Wd,
    unsigned short* __restrict__ wsu)
{
  const int idx = blockIdx.x * 256 + threadIdx.x;
  if (idx >= TOT_N) return;
  int region, l;
  if (idx < B0P_N)               { region = 0; l = idx; }
  else if (idx < B0P_N + B1P_N)  { region = 1; l = idx - B0P_N; }
  else                           { region = 2; l = idx - (B0P_N + B1P_N); }

  int k, nt, lane, j;
  if (region < 2) {
    k  = l >> 14;            // 32 tiles * 512 ushorts per ktile
    int r1 = l & 16383;
    nt = r1 >> 9;
    int li = r1 & 511;
    lane = li >> 3; j = li & 7;
  } else {
    k  = l / 2560;           // 5 * 512 per ktile
    int r1 = l % 2560;
    nt = r1 >> 9;
    int li = r1 & 511;
    lane = li >> 3; j = li & 7;
  }
  const int n  = nt * 16 + (lane & 15);
  const int kk = k * 32 + (lane >> 4) * 8 + j;

  float v = 0.f;
  if (region == 0) {
    if (kk < IN_)                    v = Wih0[n * IN_ + kk];
    else if (kk >= 96 && kk < 224)   v = Whh0[n * H_ + (kk - 96)];
  } else if (region == 1) {
    v = (kk < H_) ? Wih1[n * H_ + kk] : Whh1[n * H_ + (kk - H_)];
  } else {
    if (n < OUT_)                    v = Wd[n * H_ + kk];
  }
  wsu[idx] = bf16rn(v);
}

// ---------------- main persistent-recurrence kernel --------------------------
__global__ __launch_bounds__(512, 4) void wm_main(
    const float* __restrict__ x,
    const char*  __restrict__ wsb,
    const float* __restrict__ bih0, const float* __restrict__ bhh0,
    const float* __restrict__ bih1, const float* __restrict__ bhh1,
    const float* __restrict__ bd,
    float* __restrict__ out)
{
  __shared__ __align__(16) unsigned short A0h[BR * S0];
  __shared__ __align__(16) unsigned short A0l[BR * S0];
  __shared__ __align__(16) unsigned short A1h[BR * S1];
  __shared__ __align__(16) unsigned short A1l[BR * S1];

  const int tid  = threadIdx.x;
  const int lane = tid & 63;
  const int wv   = tid >> 6;      // wave id = unit-slice id (0..7)
  const int ln15 = lane & 15;
  const int quad = lane >> 4;
  const int lane16 = lane * 16;

  const char* B0 = wsb + B0P_OFF;
  const char* B1 = wsb + B1P_OFF;
  const char* BD = wsb + BDP_OFF;

  // zero LDS (h/c zero-init — both parity buffers; pads stay zero)
  for (int i = tid; i < BR * S0; i += 512) { A0h[i] = 0; A0l[i] = 0; }
  for (int i = tid; i < BR * S1; i += 512) { A1h[i] = 0; A1l[i] = 0; }

  // bias preload — this wave's unit col = wv*16 + ln15, per gate g
  float b0r[4], b1r[4];
  #pragma unroll
  for (int g = 0; g < 4; ++g) {
    const int n = g * 128 + wv * 16 + ln15;
    b0r[g] = bih0[n] + bhh0[n];
    b1r[g] = bih1[n] + bhh1[n];
  }
  // dense head: waves 0..4 own o-tile wv (o = wv*16 + ln15)
  const int od = wv * 16 + ln15;
  const float bdr = (wv < NTD && od < OUT_) ? bd[od] : 0.f;

  float c1[4], c2[4];
  #pragma unroll
  for (int r = 0; r < 4; ++r) { c1[r] = 0.f; c2[r] = 0.f; }

  const int a0b = ln15 * S0 + quad * 8;    // A-frag offset (row ln15)
  const int a1b = ln15 * S1 + quad * 8;
  const int prow = quad * 4;               // C/D rows = prow + r
  const int unit = wv * 16 + ln15;         // this lane's unit column

  __syncthreads();

  for (int t = 0; t < 65; ++t) {
    const int p = t & 1;        // parity buffer GEMMs read
    const int q = p ^ 1;        // parity buffer pointwise writes
    // ---- input staging: t<50 from x; t==50 reuses x[:,49,:]; t>50 pose+cond
    if (t < T_) {
      const int r  = tid >> 5;             // 16 rows x 32 lanes
      const int kk = tid & 31;
      const float* xr = x + ((size_t)(blockIdx.x * BR + r) * T_ + t) * IN_;
      for (int k = kk; k < IN_; k += 32) {
        const float v = __builtin_nontemporal_load(xr + k);
        const unsigned short hi = bf16rn(v);
        A0h[r * S0 + k] = hi;
        A0l[r * S0 + k] = bf16rn(v - bf16tof(hi));
      }
    }
    __syncthreads();   // (A) input/pose + prev h-writes visible

    // ---- layer 0 GEMM: gates0 = [u | h1[p]] x W0hi^T  (acc init = bias)
    // k-tiles 0..2 = u+pad at k*32; k-tiles 3..6 = h1[p] at k*32 + p*128
    ffrag acc0[4];
    #pragma unroll
    for (int g = 0; g < 4; ++g)
      acc0[g] = (ffrag){b0r[g], b0r[g], b0r[g], b0r[g]};
    #pragma unroll
    for (int k = 0; k < K0T; ++k) {
      const int off = a0b + k * 32 + ((k >= 3) ? p * 128 : 0);
      const bfrag ah = *(const bfrag*)(A0h + off);
      const bfrag al = *(const bfrag*)(A0l + off);
      #pragma unroll
      for (int g = 0; g < 4; ++g) {
        const bfrag bh =
            *(const bfrag*)(B0 + (size_t)(k * NT0 + g * 8 + wv) * 1024 + lane16);
        MFMA(acc0[g], ah, bh);
        MFMA(acc0[g], al, bh);
      }
    }

    // ---- layer 0 pointwise: all 4 gates in-lane; write h1 into parity q
    #pragma unroll
    for (int r = 0; r < 4; ++r) {
      const float ig = sigmoid_f(acc0[0][r]);
      const float fg = sigmoid_f(acc0[1][r]);
      const float gg = tanh_f(acc0[2][r]);
      const float og = sigmoid_f(acc0[3][r]);
      const float c  = fmaf(fg, c1[r], ig * gg);
      c1[r] = c;
      const float h  = og * tanh_f(c);
      const unsigned short hi = bf16rn(h);
      const unsigned short lo = bf16rn(h - bf16tof(hi));
      const int row = prow + r;
      A0h[row * S0 + 96 + q * 128 + unit] = hi;   // next step's h1
      A0l[row * S0 + 96 + q * 128 + unit] = lo;
      A1h[row * S1 + unit] = hi;                  // this step's L1 input
      A1l[row * S1 + unit] = lo;
    }
    __syncthreads();   // (C) h1 visible for layer 1

    // ---- layer 1 GEMM: gates1 = [h1 | h2[p]] x W1hi^T
    // k-tiles 0..3 = h1 at k*32; k-tiles 4..7 = h2[p] at k*32 + p*128
    ffrag acc1[4];
    #pragma unroll
    for (int g = 0; g < 4; ++g)
      acc1[g] = (ffrag){b1r[g], b1r[g], b1r[g], b1r[g]};
    #pragma unroll
    for (int k = 0; k < K1T; ++k) {
      const int off = a1b + k * 32 + ((k >= 4) ? p * 128 : 0);
      const bfrag ah = *(const bfrag*)(A1h + off);
      const bfrag al = *(const bfrag*)(A1l + off);
      #pragma unroll
      for (int g = 0; g < 4; ++g) {
        const bfrag bh =
            *(const bfrag*)(B1 + (size_t)(k * NT1 + g * 8 + wv) * 1024 + lane16);
        MFMA(acc1[g], ah, bh);
        MFMA(acc1[g], al, bh);
      }
    }

    // ---- layer 1 pointwise: write h2 into parity q (no barrier needed —
    // GEMM read parity p; next step's read of q is ordered by (A)+(C))
    #pragma unroll
    for (int r = 0; r < 4; ++r) {
      const float ig = sigmoid_f(acc1[0][r]);
      const float fg = sigmoid_f(acc1[1][r]);
      const float gg = tanh_f(acc1[2][r]);
      const float og = sigmoid_f(acc1[3][r]);
      const float c  = fmaf(fg, c2[r], ig * gg);
      c2[r] = c;
      const float h  = og * tanh_f(c);
      const unsigned short hi = bf16rn(h);
      const unsigned short lo = bf16rn(h - bf16tof(hi));
      const int row = prow + r;
      A1h[row * S1 + 128 + q * 128 + unit] = hi;
      A1l[row * S1 + 128 + q * 128 + unit] = lo;
    }

    // ---- dense head + pose feedback (t >= 50)
    if (t >= T_) {
      __syncthreads();   // (E) new h2 (parity q) visible
      const int s = t - T_;
      if (wv < NTD) {
        ffrag dacc = (ffrag){bdr, bdr, bdr, bdr};
        #pragma unroll
        for (int k = 0; k < KDT; ++k) {
          const int off = a1b + 128 + q * 128 + k * 32;
          const bfrag ah = *(const bfrag*)(A1h + off);
          const bfrag al = *(const bfrag*)(A1l + off);
          const bfrag bh =
              *(const bfrag*)(BD + (size_t)(k * NTD + wv) * 1024 + lane16);
          MFMA(dacc, ah, bh);
          MFMA(dacc, al, bh);
        }
        if (od < OUT_) {
          #pragma unroll
          for (int r = 0; r < 4; ++r) {
            const int row = prow + r;
            const float v = dacc[r];
            __builtin_nontemporal_store(
                v, &out[((size_t)(blockIdx.x * BR + row) * NPOSE + s) * OUT_ + od]);
            if (s < NPOSE - 1) {
              const unsigned short hi = bf16rn(v);
              A0h[row * S0 + od] = hi;       // next pose input (u region)
              A0l[row * S0 + od] = bf16rn(v - bf16tof(hi));
            }
          }
        }
      }
      // pose writes ordered vs next step's L0 GEMM by barrier (A)
    }
  }
}

extern "C" void kernel_launch(void* const* d_in, const int* in_sizes, int n_in,
                              void* d_out, int out_size, void* d_ws, size_t ws_size,
                              hipStream_t stream)
{
  const float* x    = (const float*)d_in[0];
  const float* Wih0 = (const float*)d_in[1];
  const float* Whh0 = (const float*)d_in[2];
  const float* bih0 = (const float*)d_in[3];
  const float* bhh0 = (const float*)d_in[4];
  const float* Wih1 = (const float*)d_in[5];
  const float* Whh1 = (const float*)d_in[6];
  const float* bih1 = (const float*)d_in[7];
  const float* bhh1 = (const float*)d_in[8];
  const float* Wd   = (const float*)d_in[9];
  const float* bd   = (const float*)d_in[10];

  wm_prep<<<(TOT_N + 255) / 256, 256, 0, stream>>>(Wih0, Whh0, Wih1, Whh1, Wd,
                                                   (unsigned short*)d_ws);
  wm_main<<<B_ / BR, 512, 0, stream>>>(x, (const char*)d_ws,
                                       bih0, bhh0, bih1, bhh1, bd,
                                       (float*)d_out);
}